// Round 16
// baseline (76.493 us; speedup 1.0000x reference)
//
#include <hip/hip_runtime.h>
#include <cstdint>
#include <cstddef>

typedef __attribute__((ext_vector_type(8))) short short8;
typedef __attribute__((ext_vector_type(4))) float f32x4;

#define GLOAD_LDS16(gsrc, ldst) \
    __builtin_amdgcn_global_load_lds( \
        (const __attribute__((address_space(1))) void*)(gsrc), \
        (__attribute__((address_space(3))) void*)(ldst), 16, 0, 0)

namespace {
constexpr int kN    = 65536;     // nodes
constexpr int kF    = 256;       // feats
constexpr int kC    = 64;        // pools per graph
constexpr int kNPG  = 1024;      // nodes per graph
constexpr int kB    = 64;        // graphs
constexpr int kE    = 2097152;   // edges
constexpr int kK    = kB * kC;   // 4096 global clusters

// d_out offsets (in floats)
constexpr size_t OFF_OUT  = 0;                           // [4096,256]
constexpr size_t OFF_EIDX = (size_t)kK * kF;             // 1048576  [2,262144]
constexpr size_t OFF_ADJ  = OFF_EIDX + 2ull*kB*kC*kC;    // 1572864  [262144]
constexpr size_t OFF_LL   = OFF_ADJ + (size_t)kB*kC*kC;  // 1835008
constexpr size_t OFF_Z    = OFF_LL + 1;                  // 1835009
constexpr size_t OFF_BOUT = OFF_Z + 1;                   // 1835010  [4096]
constexpr size_t OFF_BPTR = OFF_BOUT + kK;               // 1839106  [65]

// ws offsets (bytes). Overlaps stream-time-disjoint (WPH/WPL + PERM/STRT die
// before k_adj writes PADJ over the same range).
constexpr size_t WS_C    = 0;        // int[65536]
constexpr size_t WS_V    = 262144;   // float[65536]
constexpr size_t WS_VS2  = 524288;   // float[4096]
constexpr size_t WS_A2   = 540672;   // float[512]
constexpr size_t WS_PERM = 544768;   // int[65536]
constexpr size_t WS_STRT = 806912;   // int[64*65]
constexpr size_t WS_WPH  = 1048576;  // ushort[16384] W frag-packed hi
constexpr size_t WS_WPL  = 1081344;  // ushort[16384] W frag-packed lo
constexpr size_t WS_PADJ = 544768;   // float[512*4096] = 8 MiB (k_adj onward)

__device__ __forceinline__ unsigned short bf16_rn(float f)
{
    const unsigned int b = __float_as_uint(f);
    return (unsigned short)((b + 0x7fffu + ((b >> 16) & 1u)) >> 16);
}
} // namespace

// ---------------------------------------------------------------- constants
// + packs W into MFMA B-fragment order, bf16 hi/lo:
//   wpack[((ks*4+nt)*64 + lane)*8 + j]  <-  W[(ks*32+(lane>>4)*8+j)*64
//                                             + nt*16 + (lane&15)]
__global__ __launch_bounds__(256) void k_const(float* __restrict__ out,
                                               const float* __restrict__ Wm,
                                               unsigned short* __restrict__ wph,
                                               unsigned short* __restrict__ wpl)
{
    const int i = blockIdx.x * 256 + threadIdx.x;
    constexpr int E2 = 2 * kB * kC * kC;      // 524288
    constexpr int B3 = E2 + kK + kB + 1;      // 528449
    if (i < E2) {
        const int half = i >= kB*kC*kC;
        const int idx  = half ? i - kB*kC*kC : i;
        const int bb = idx >> 12, rem = idx & 4095;
        const int val = half ? bb*kC + (rem & 63) : bb*kC + (rem >> 6);
        out[OFF_EIDX + i] = (float)val;
    } else if (i < E2 + kK) {
        const int j = i - E2;
        out[OFF_BOUT + j] = (float)(j >> 6);
    } else if (i < B3) {
        const int j = i - (E2 + kK);
        out[OFF_BPTR + j] = (float)(j * kC);
    } else if (i < B3 + 32768) {
        const int j  = (i - B3) & 16383;
        const int lo = (i - B3) >= 16384;
        const int jj = j & 7, lane = (j >> 3) & 63;
        const int nt = (j >> 9) & 3, ks = j >> 11;
        const float wv = Wm[(size_t)(ks*32 + (lane>>4)*8 + jj)*kC
                            + nt*16 + (lane & 15)];
        const unsigned short h = bf16_rn(wv);
        if (!lo) {
            wph[j] = h;
        } else {
            const float hf = __uint_as_float((unsigned int)h << 16);
            wpl[j] = bf16_rn(wv - hf);
        }
    }
}

// ------------------------------------------------- K1: logits -> c, v
// Barrier-free per-wave pipelined MFMA.
//  * W lives in LDS (copied once in prologue) -> in-loop W fragment reads
//    are ds_read_b128 on LGKMcnt; the VMcnt stream holds ONLY x stage
//    loads, so the counted vmcnt(2) actually keeps chunk c+1 in flight
//    (rounds 14/15 bug: W global loads issued after the prefetch forced
//    an implicit vmcnt(0) every chunk -- vmcnt retires in order).
//  * Each wave stages & consumes ONLY its own 16-row x slice -> no
//    __syncthreads in the main loop (no structural barrier drain).
// Numerics identical to rounds 13-15 (same split, same MFMA order).
__global__ __launch_bounds__(256) void k_logits(
    const float* __restrict__ x, const unsigned short* __restrict__ wph,
    const unsigned short* __restrict__ wpl, const float* __restrict__ bv,
    int* __restrict__ carr, float* __restrict__ varr)
{
    __shared__ unsigned short wlds[32768];   // 64 KB: [0..16383]=hi, rest=lo
    __shared__ float xsl[2][64 * 32];        // 2 x 8 KB, [node][8 slots x 4f]
    const int tid  = threadIdx.x;
    const int lane = tid & 63;
    const int w    = tid >> 6;          // wave 0..3
    const int nbase = blockIdx.x * 64;
    const int l15  = lane & 15;
    const int kgrp = lane >> 4;         // 0..3

    // x staging: wave w owns rows w*16..w*16+15; instr i covers rows
    // i*8+(l>>3); phys slot l&7 holds k-slot (l&7)^(row&7)  [T2, rule #21]
    const int snode = lane >> 3;                     // row&7
    const int sfo   = ((lane & 7) ^ snode) * 4;      // source float offset

    f32x4 acc[4];
#pragma unroll
    for (int nt = 0; nt < 4; ++nt) acc[nt] = f32x4{0.f, 0.f, 0.f, 0.f};

    // ---- prologue: W -> LDS (16 instrs) + x chunk 0 (2 instrs), then one
    // full drain + barrier (one-time cost).
#pragma unroll
    for (int t = 0; t < 8; ++t) {
        GLOAD_LDS16(wph + ((size_t)t*256 + tid)*8,
                    &wlds[(t*256 + w*64)*8]);
        GLOAD_LDS16(wpl + ((size_t)t*256 + tid)*8,
                    &wlds[16384 + (t*256 + w*64)*8]);
    }
#pragma unroll
    for (int i = 0; i < 2; ++i) {
        const float* src = x + (size_t)(nbase + w*16 + i*8 + snode)*kF + sfo;
        GLOAD_LDS16(src, &xsl[0][(w*16 + i*8)*32]);
    }
    asm volatile("s_waitcnt vmcnt(0)" ::: "memory");
    __syncthreads();   // W visible to all waves (staged cooperatively)

#pragma unroll 1
    for (int c = 0; c < 8; ++c) {
        if (c < 7) {
#pragma unroll
            for (int i = 0; i < 2; ++i) {
                const float* src = x + (size_t)(nbase + w*16 + i*8 + snode)*kF
                                     + (c+1)*32 + sfo;
                GLOAD_LDS16(src, &xsl[(c+1) & 1][(w*16 + i*8)*32]);
            }
            asm volatile("s_waitcnt vmcnt(2)" ::: "memory");
        } else {
            asm volatile("s_waitcnt vmcnt(0)" ::: "memory");
        }

        const float* __restrict__ xb = &xsl[c & 1][0];
        // W fragments from LDS: lane-contiguous 16B -> even-bank floor
        short8 bh[4], bl[4];
#pragma unroll
        for (int nt = 0; nt < 4; ++nt) {
            const int wo = ((c*4 + nt)*64 + lane) * 8;
            bh[nt] = *reinterpret_cast<const short8*>(&wlds[wo]);
            bl[nt] = *reinterpret_cast<const short8*>(&wlds[16384 + wo]);
        }
        // x fragment: row w*16+l15, swizzled slots
        const int row = w*16 + l15;
        const int sA  = ((kgrp*2)     ^ (l15 & 7)) * 4;
        const int sC  = ((kgrp*2 + 1) ^ (l15 & 7)) * 4;
        const float4 xa = *reinterpret_cast<const float4*>(&xb[row*32 + sA]);
        const float4 xc = *reinterpret_cast<const float4*>(&xb[row*32 + sC]);
        const float xv[8] = {xa.x, xa.y, xa.z, xa.w,
                             xc.x, xc.y, xc.z, xc.w};
        short8 ah, al;
#pragma unroll
        for (int j = 0; j < 8; ++j) {
            const unsigned short h = bf16_rn(xv[j]);
            const float hf = __uint_as_float((unsigned int)h << 16);
            ah[j] = (short)h;
            al[j] = (short)bf16_rn(xv[j] - hf);
        }
#pragma unroll
        for (int nt = 0; nt < 4; ++nt) {
            acc[nt] = __builtin_amdgcn_mfma_f32_16x16x32_bf16(
                ah, bh[nt], acc[nt], 0, 0, 0);
            acc[nt] = __builtin_amdgcn_mfma_f32_16x16x32_bf16(
                al, bh[nt], acc[nt], 0, 0, 0);
            acc[nt] = __builtin_amdgcn_mfma_f32_16x16x32_bf16(
                ah, bl[nt], acc[nt], 0, 0, 0);
            acc[nt] = __builtin_amdgcn_mfma_f32_16x16x32_bf16(
                al, bl[nt], acc[nt], 0, 0, 0);
        }
    }

    // bias + per-node softmax-argmax (D: col=nt*16+l15, row=kgrp*4+r)
#pragma unroll
    for (int nt = 0; nt < 4; ++nt) {
        const float b = bv[nt*16 + l15];
#pragma unroll
        for (int r = 0; r < 4; ++r) acc[nt][r] += b;
    }
#pragma unroll
    for (int r = 0; r < 4; ++r) {
        float m = acc[0][r]; int ci = l15;
#pragma unroll
        for (int nt = 1; nt < 4; ++nt) {
            if (acc[nt][r] > m) { m = acc[nt][r]; ci = nt*16 + l15; }
        }
#pragma unroll
        for (int off = 1; off < 16; off <<= 1) {
            const float om = __shfl_xor(m, off);
            const int   oc = __shfl_xor(ci, off);
            if (om > m || (om == m && oc < ci)) { m = om; ci = oc; }
        }
        float s = 0.f;
#pragma unroll
        for (int nt = 0; nt < 4; ++nt) s += expf(acc[nt][r] - m);
#pragma unroll
        for (int off = 1; off < 16; off <<= 1) s += __shfl_xor(s, off);
        if (l15 == r) {
            const float p = 1.0f / s;
            const int n = nbase + w*16 + kgrp*4 + r;
            carr[n] = ci;
            varr[n] = (1.0f - p) + p;   // straight-through forward
        }
    }
}

// ------------------------------------- K1b: deterministic stable counting sort
__global__ __launch_bounds__(1024) void k_sort(
    const int* __restrict__ carr, int* __restrict__ perm,
    int* __restrict__ startc)
{
    __shared__ int hist[16][64];
    __shared__ int startS[65];
    const int g = blockIdx.x;
    const int tid = threadIdx.x;
    const int w = tid >> 6, lane = tid & 63;
    const int c = carr[g*kNPG + tid];
    hist[tid >> 6][tid & 63] = 0;
    __syncthreads();
    unsigned long long mm = ~0ull;
#pragma unroll
    for (int b = 0; b < 6; ++b) {
        const unsigned long long bal = __ballot((c >> b) & 1);
        mm &= ((c >> b) & 1) ? bal : ~bal;
    }
    const unsigned long long ltmask =
        (lane == 0) ? 0ull : (~0ull >> (64 - lane));
    const int rank_in_wave = __popcll(mm & ltmask);
    const int leader = __ffsll((unsigned long long)mm) - 1;
    if (lane == leader) hist[w][c] = __popcll(mm);
    __syncthreads();
    if (w == 0) {
        int tot = 0;
#pragma unroll
        for (int i = 0; i < 16; ++i) tot += hist[i][lane];
        int pre = tot;
#pragma unroll
        for (int off = 1; off < 64; off <<= 1) {
            const int t = __shfl_up(pre, off);
            if (lane >= off) pre += t;
        }
        startS[lane + 1] = pre;
        if (lane == 0) startS[0] = 0;
    }
    __syncthreads();
    int before = startS[c];
    for (int i = 0; i < w; ++i) before += hist[i][c];
    perm[g*kNPG + before + rank_in_wave] = g*kNPG + tid;
    if (tid < 65) startc[g*65 + tid] = startS[tid];
}

// ------------------------------------- K2: out = S^T x (+ vs2) — atomic-FREE
__global__ __launch_bounds__(1024) void k_pool_x(
    const float* __restrict__ x, const int* __restrict__ perm,
    const int* __restrict__ startc, const float* __restrict__ varr,
    float* __restrict__ out, float* __restrict__ vs2)
{
    const int tid  = threadIdx.x;
    const int g    = blockIdx.x >> 3;
    const int fh   = blockIdx.x & 7;
    const int w    = tid >> 6;
    const int lane = tid & 63;
    const int q    = lane & 7;      // feat quad (float4)
    const int sub  = lane >> 3;     // node slot 0..7
    const int fbase = fh*32 + q*4;
#pragma unroll
    for (int cc = 0; cc < 4; ++cc) {
        const int c = w*4 + cc;
        const int s = startc[g*65 + c];
        const int e = startc[g*65 + c + 1];
        float ax = 0.f, ay = 0.f, az = 0.f, aw = 0.f, v2 = 0.f;
        for (int base = s + sub; base < e; base += 8) {
            const int n = perm[(size_t)g*kNPG + base];
            const float v = varr[n];
            const float4 xv = *reinterpret_cast<const float4*>(
                x + (size_t)n*kF + fbase);
            ax = fmaf(v, xv.x, ax); ay = fmaf(v, xv.y, ay);
            az = fmaf(v, xv.z, az); aw = fmaf(v, xv.w, aw);
            v2 = fmaf(v, v, v2);
        }
#pragma unroll
        for (int off = 8; off < 64; off <<= 1) {
            ax += __shfl_xor(ax, off); ay += __shfl_xor(ay, off);
            az += __shfl_xor(az, off); aw += __shfl_xor(aw, off);
            v2 += __shfl_xor(v2, off);
        }
        if (sub == 0) {
            const float4 o = {ax, ay, az, aw};
            *reinterpret_cast<float4*>(
                out + OFF_OUT + (size_t)(g*kC + c)*kF + fbase) = o;
        }
        if (fh == 0 && lane == 0) vs2[g*kC + c] = v2;
    }
}

// ------------------------------------- K4: adjacency partials (+ a2 partial)
__global__ __launch_bounds__(1024) void k_adj(
    const int* __restrict__ ei, const float* __restrict__ ew,
    const int* __restrict__ carr, const float* __restrict__ varr,
    float* __restrict__ padj, float* __restrict__ a2p)
{
    __shared__ float adj[kC*kC];   // 16 KB
    __shared__ float vls[kNPG];    // 4 KB
    __shared__ int   cls[kNPG];    // 4 KB
    __shared__ float wred[16];
    const int tid = threadIdx.x;
    const int bid = blockIdx.x;             // 512 blocks = 64 graphs x 8
    const int g   = bid >> 3;
    for (int i = tid; i < kC*kC; i += 1024) adj[i] = 0.f;
    vls[tid] = varr[g*kNPG + tid];
    cls[tid] = carr[g*kNPG + tid];
    __syncthreads();
    const int e0 = bid * 4096;
    float a2l = 0.f;
#pragma unroll
    for (int it = 0; it < 4; ++it) {
        const int e  = e0 + it*1024 + tid;
        const int sn = ei[e]      & (kNPG - 1);
        const int dn = ei[kE + e] & (kNPG - 1);
        const float wv = ew[e];
        a2l += wv * wv;
        atomicAdd(&adj[cls[sn]*kC + cls[dn]], wv * vls[sn] * vls[dn]);
    }
    __syncthreads();
#pragma unroll
    for (int r = 0; r < 4; ++r) {
        const int lin = r*1024 + tid;
        padj[(size_t)bid*4096 + lin] = adj[lin];
    }
#pragma unroll
    for (int off = 32; off > 0; off >>= 1) a2l += __shfl_down(a2l, off);
    if ((tid & 63) == 0) wred[tid >> 6] = a2l;
    __syncthreads();
    if (tid == 0) {
        float s = 0.f;
#pragma unroll
        for (int wv = 0; wv < 16; ++wv) s += wred[wv];
        a2p[bid] = s;
    }
}

// ------------------------------------- K5: merge adjacency partials (x8)
__global__ __launch_bounds__(256) void k_adj_merge(
    const float* __restrict__ padj, float* __restrict__ out)
{
    const int id = blockIdx.x*256 + threadIdx.x;   // < 262144
    const int g = id >> 12, idx = id & 4095;
    float s = 0.f;
#pragma unroll
    for (int sp = 0; sp < 8; ++sp) s += padj[(size_t)(g*8 + sp)*4096 + idx];
    out[OFF_ADJ + id] = s;
}

// ------------------------------------- K6: link_loss scalar
__global__ __launch_bounds__(256) void k_final(
    const float* __restrict__ vs2, const float* __restrict__ a2p,
    float* __restrict__ out)
{
    const int tid = threadIdx.x;
    float p2l = 0.f, apl = 0.f;
#pragma unroll
    for (int r = 0; r < 16; ++r) {
        const int k = r*256 + tid;
        const float t = vs2[k];
        p2l += t*t;
        const int g = k >> 6, cc = k & 63;
        apl += out[OFF_ADJ + (size_t)g*4096 + cc*65];   // diagonal entries
    }
    float a2l = a2p[tid] + a2p[tid + 256];
#pragma unroll
    for (int off = 32; off > 0; off >>= 1) {
        p2l += __shfl_down(p2l, off);
        apl += __shfl_down(apl, off);
        a2l += __shfl_down(a2l, off);
    }
    __shared__ float red[3][4];
    if ((tid & 63) == 0) {
        red[0][tid>>6] = p2l; red[1][tid>>6] = apl; red[2][tid>>6] = a2l;
    }
    __syncthreads();
    if (tid == 0) {
        const float p2 = red[0][0]+red[0][1]+red[0][2]+red[0][3];
        const float ap = red[1][0]+red[1][1]+red[1][2]+red[1][3];
        const float a2 = red[2][0]+red[2][1]+red[2][2]+red[2][3];
        const float val = a2 - 2.0f*ap + p2;
        out[OFF_LL] = sqrtf(fmaxf(val, 0.f)) / (float)kE;
        out[OFF_Z]  = 0.0f;
    }
}

// ----------------------------------------------------------------- launch
extern "C" void kernel_launch(void* const* d_in, const int* in_sizes, int n_in,
                              void* d_out, int out_size, void* d_ws, size_t ws_size,
                              hipStream_t stream)
{
    const float* x  = (const float*)d_in[0];
    const int*   ei = (const int*)d_in[1];
    const float* ew = (const float*)d_in[2];
    const float* Wm = (const float*)d_in[5];
    const float* bv = (const float*)d_in[6];
    float* out = (float*)d_out;
    char*  ws  = (char*)d_ws;
    int*   carr  = (int*)(ws + WS_C);
    float* varr  = (float*)(ws + WS_V);
    float* vs2   = (float*)(ws + WS_VS2);
    float* a2p   = (float*)(ws + WS_A2);
    int*   perm  = (int*)(ws + WS_PERM);
    int*   strt  = (int*)(ws + WS_STRT);
    unsigned short* wph = (unsigned short*)(ws + WS_WPH);
    unsigned short* wpl = (unsigned short*)(ws + WS_WPL);
    float* padj  = (float*)(ws + WS_PADJ);

    k_const    <<<2193, 256, 0, stream>>>(out, Wm, wph, wpl);
    k_logits   <<<1024, 256, 0, stream>>>(x, wph, wpl, bv, carr, varr);
    k_sort     <<<64,  1024, 0, stream>>>(carr, perm, strt);
    k_pool_x   <<<512, 1024, 0, stream>>>(x, perm, strt, varr, out, vs2);
    k_adj      <<<512, 1024, 0, stream>>>(ei, ew, carr, varr, padj, a2p);
    k_adj_merge<<<1024, 256, 0, stream>>>(padj, out);
    k_final    <<<1,    256, 0, stream>>>(vs2, a2p, out);
}

// Round 17
// 66.304 us; speedup vs baseline: 1.1537x; 1.1537x over previous
//
#include <hip/hip_runtime.h>
#include <cstdint>
#include <cstddef>

typedef __attribute__((ext_vector_type(8))) short short8;
typedef __attribute__((ext_vector_type(4))) float f32x4;

#define GLOAD_LDS16(gsrc, ldst) \
    __builtin_amdgcn_global_load_lds( \
        (const __attribute__((address_space(1))) void*)(gsrc), \
        (__attribute__((address_space(3))) void*)(ldst), 16, 0, 0)

namespace {
constexpr int kN    = 65536;     // nodes
constexpr int kF    = 256;       // feats
constexpr int kC    = 64;        // pools per graph
constexpr int kNPG  = 1024;      // nodes per graph
constexpr int kB    = 64;        // graphs
constexpr int kE    = 2097152;   // edges
constexpr int kK    = kB * kC;   // 4096 global clusters

// d_out offsets (in floats)
constexpr size_t OFF_OUT  = 0;                           // [4096,256]
constexpr size_t OFF_EIDX = (size_t)kK * kF;             // 1048576  [2,262144]
constexpr size_t OFF_ADJ  = OFF_EIDX + 2ull*kB*kC*kC;    // 1572864  [262144]
constexpr size_t OFF_LL   = OFF_ADJ + (size_t)kB*kC*kC;  // 1835008
constexpr size_t OFF_Z    = OFF_LL + 1;                  // 1835009
constexpr size_t OFF_BOUT = OFF_Z + 1;                   // 1835010  [4096]
constexpr size_t OFF_BPTR = OFF_BOUT + kK;               // 1839106  [65]

// ws offsets (bytes). WPH/WPL die after k_logits; k_fused then writes PADJ.
constexpr size_t WS_C    = 0;        // int[65536]
constexpr size_t WS_V    = 262144;   // float[65536]
constexpr size_t WS_VS2  = 524288;   // float[4096]
constexpr size_t WS_A2   = 540672;   // float[512]
constexpr size_t WS_WPH  = 1048576;  // ushort[16384] W frag-packed hi
constexpr size_t WS_WPL  = 1081344;  // ushort[16384] W frag-packed lo
constexpr size_t WS_PADJ = 1114112;  // float[512*4096] = 8 MiB
constexpr size_t WS_DSUM = 9502720;  // float[1024] diag partials

__device__ __forceinline__ unsigned short bf16_rn(float f)
{
    const unsigned int b = __float_as_uint(f);
    return (unsigned short)((b + 0x7fffu + ((b >> 16) & 1u)) >> 16);
}
} // namespace

// ---------------------------------------------------------------- constants
// + packs W into MFMA B-fragment order, bf16 hi/lo.
__global__ __launch_bounds__(256) void k_const(float* __restrict__ out,
                                               const float* __restrict__ Wm,
                                               unsigned short* __restrict__ wph,
                                               unsigned short* __restrict__ wpl)
{
    const int i = blockIdx.x * 256 + threadIdx.x;
    constexpr int E2 = 2 * kB * kC * kC;      // 524288
    constexpr int B3 = E2 + kK + kB + 1;      // 528449
    if (i < E2) {
        const int half = i >= kB*kC*kC;
        const int idx  = half ? i - kB*kC*kC : i;
        const int bb = idx >> 12, rem = idx & 4095;
        const int val = half ? bb*kC + (rem & 63) : bb*kC + (rem >> 6);
        out[OFF_EIDX + i] = (float)val;
    } else if (i < E2 + kK) {
        const int j = i - E2;
        out[OFF_BOUT + j] = (float)(j >> 6);
    } else if (i < B3) {
        const int j = i - (E2 + kK);
        out[OFF_BPTR + j] = (float)(j * kC);
    } else if (i < B3 + 32768) {
        const int j  = (i - B3) & 16383;
        const int lo = (i - B3) >= 16384;
        const int jj = j & 7, lane = (j >> 3) & 63;
        const int nt = (j >> 9) & 3, ks = j >> 11;
        const float wv = Wm[(size_t)(ks*32 + (lane>>4)*8 + jj)*kC
                            + nt*16 + (lane & 15)];
        const unsigned short h = bf16_rn(wv);
        if (!lo) {
            wph[j] = h;
        } else {
            const float hf = __uint_as_float((unsigned int)h << 16);
            wpl[j] = bf16_rn(wv - hf);
        }
    }
}

// ------------------------------------------------- K1: logits -> c, v
// (round-16 structure: W in LDS via one-time prologue stage; barrier-free
// main loop; per-wave x double-buffer with counted vmcnt(2); T2 swizzle.)
__global__ __launch_bounds__(256) void k_logits(
    const float* __restrict__ x, const unsigned short* __restrict__ wph,
    const unsigned short* __restrict__ wpl, const float* __restrict__ bv,
    int* __restrict__ carr, float* __restrict__ varr)
{
    __shared__ unsigned short wlds[32768];   // 64 KB: [0..16383]=hi, rest=lo
    __shared__ float xsl[2][64 * 32];        // 2 x 8 KB
    const int tid  = threadIdx.x;
    const int lane = tid & 63;
    const int w    = tid >> 6;
    const int nbase = blockIdx.x * 64;
    const int l15  = lane & 15;
    const int kgrp = lane >> 4;

    const int snode = lane >> 3;
    const int sfo   = ((lane & 7) ^ snode) * 4;

    f32x4 acc[4];
#pragma unroll
    for (int nt = 0; nt < 4; ++nt) acc[nt] = f32x4{0.f, 0.f, 0.f, 0.f};

#pragma unroll
    for (int t = 0; t < 8; ++t) {
        GLOAD_LDS16(wph + ((size_t)t*256 + tid)*8, &wlds[(t*256 + w*64)*8]);
        GLOAD_LDS16(wpl + ((size_t)t*256 + tid)*8,
                    &wlds[16384 + (t*256 + w*64)*8]);
    }
#pragma unroll
    for (int i = 0; i < 2; ++i) {
        const float* src = x + (size_t)(nbase + w*16 + i*8 + snode)*kF + sfo;
        GLOAD_LDS16(src, &xsl[0][(w*16 + i*8)*32]);
    }
    asm volatile("s_waitcnt vmcnt(0)" ::: "memory");
    __syncthreads();

#pragma unroll 1
    for (int c = 0; c < 8; ++c) {
        if (c < 7) {
#pragma unroll
            for (int i = 0; i < 2; ++i) {
                const float* src = x + (size_t)(nbase + w*16 + i*8 + snode)*kF
                                     + (c+1)*32 + sfo;
                GLOAD_LDS16(src, &xsl[(c+1) & 1][(w*16 + i*8)*32]);
            }
            asm volatile("s_waitcnt vmcnt(2)" ::: "memory");
        } else {
            asm volatile("s_waitcnt vmcnt(0)" ::: "memory");
        }

        const float* __restrict__ xb = &xsl[c & 1][0];
        short8 bh[4], bl[4];
#pragma unroll
        for (int nt = 0; nt < 4; ++nt) {
            const int wo = ((c*4 + nt)*64 + lane) * 8;
            bh[nt] = *reinterpret_cast<const short8*>(&wlds[wo]);
            bl[nt] = *reinterpret_cast<const short8*>(&wlds[16384 + wo]);
        }
        const int row = w*16 + l15;
        const int sA  = ((kgrp*2)     ^ (l15 & 7)) * 4;
        const int sC  = ((kgrp*2 + 1) ^ (l15 & 7)) * 4;
        const float4 xa = *reinterpret_cast<const float4*>(&xb[row*32 + sA]);
        const float4 xc = *reinterpret_cast<const float4*>(&xb[row*32 + sC]);
        const float xv[8] = {xa.x, xa.y, xa.z, xa.w,
                             xc.x, xc.y, xc.z, xc.w};
        short8 ah, al;
#pragma unroll
        for (int j = 0; j < 8; ++j) {
            const unsigned short h = bf16_rn(xv[j]);
            const float hf = __uint_as_float((unsigned int)h << 16);
            ah[j] = (short)h;
            al[j] = (short)bf16_rn(xv[j] - hf);
        }
#pragma unroll
        for (int nt = 0; nt < 4; ++nt) {
            acc[nt] = __builtin_amdgcn_mfma_f32_16x16x32_bf16(
                ah, bh[nt], acc[nt], 0, 0, 0);
            acc[nt] = __builtin_amdgcn_mfma_f32_16x16x32_bf16(
                al, bh[nt], acc[nt], 0, 0, 0);
            acc[nt] = __builtin_amdgcn_mfma_f32_16x16x32_bf16(
                ah, bl[nt], acc[nt], 0, 0, 0);
            acc[nt] = __builtin_amdgcn_mfma_f32_16x16x32_bf16(
                al, bl[nt], acc[nt], 0, 0, 0);
        }
    }

#pragma unroll
    for (int nt = 0; nt < 4; ++nt) {
        const float b = bv[nt*16 + l15];
#pragma unroll
        for (int r = 0; r < 4; ++r) acc[nt][r] += b;
    }
#pragma unroll
    for (int r = 0; r < 4; ++r) {
        float m = acc[0][r]; int ci = l15;
#pragma unroll
        for (int nt = 1; nt < 4; ++nt) {
            if (acc[nt][r] > m) { m = acc[nt][r]; ci = nt*16 + l15; }
        }
#pragma unroll
        for (int off = 1; off < 16; off <<= 1) {
            const float om = __shfl_xor(m, off);
            const int   oc = __shfl_xor(ci, off);
            if (om > m || (om == m && oc < ci)) { m = om; ci = oc; }
        }
        float s = 0.f;
#pragma unroll
        for (int nt = 0; nt < 4; ++nt) s += expf(acc[nt][r] - m);
#pragma unroll
        for (int off = 1; off < 16; off <<= 1) s += __shfl_xor(s, off);
        if (l15 == r) {
            const float p = 1.0f / s;
            const int n = nbase + w*16 + kgrp*4 + r;
            carr[n] = ci;
            varr[n] = (1.0f - p) + p;
        }
    }
}

// ------------------------------------- K2: fused pool+adj (1024 blocks)
// bid < 512: out = S^T x (+ vs2), with IN-BLOCK counting sort (no k_sort
//            launch, no perm/strt globals; same ballot algorithm ->
//            bit-identical perm -> deterministic).
// bid >= 512: adjacency partials (+ a2) — overlaps pool blocks across CUs.
__global__ __launch_bounds__(1024) void k_fused(
    const float* __restrict__ x, const int* __restrict__ carr,
    const float* __restrict__ varr, const int* __restrict__ ei,
    const float* __restrict__ ew, float* __restrict__ out,
    float* __restrict__ vs2, float* __restrict__ padj,
    float* __restrict__ a2p)
{
    __shared__ char smem[25152];
    const int tid = threadIdx.x;
    const int bid = blockIdx.x;

    if (bid < 512) {
        // ---------------- pool path: g = bid>>3, feat-eighth fh = bid&7
        int* hist   = (int*)smem;            // [16][64]
        int* startS = hist + 1024;           // [65]
        int* permL  = startS + 80;           // [1024] (80 pads alignment)
        const int g  = bid >> 3;
        const int fh = bid & 7;
        const int w = tid >> 6, lane = tid & 63;

        // --- phase A: counting sort (identical to old k_sort)
        const int c = carr[g*kNPG + tid];
        hist[tid] = 0;
        __syncthreads();
        unsigned long long mm = ~0ull;
#pragma unroll
        for (int b = 0; b < 6; ++b) {
            const unsigned long long bal = __ballot((c >> b) & 1);
            mm &= ((c >> b) & 1) ? bal : ~bal;
        }
        const unsigned long long ltmask =
            (lane == 0) ? 0ull : (~0ull >> (64 - lane));
        const int rank_in_wave = __popcll(mm & ltmask);
        const int leader = __ffsll((unsigned long long)mm) - 1;
        if (lane == leader) hist[w*64 + c] = __popcll(mm);
        __syncthreads();
        if (w == 0) {
            int tot = 0;
#pragma unroll
            for (int i = 0; i < 16; ++i) tot += hist[i*64 + lane];
            int pre = tot;
#pragma unroll
            for (int off = 1; off < 64; off <<= 1) {
                const int t = __shfl_up(pre, off);
                if (lane >= off) pre += t;
            }
            startS[lane + 1] = pre;
            if (lane == 0) startS[0] = 0;
        }
        __syncthreads();
        int before = startS[c];
        for (int i = 0; i < w; ++i) before += hist[i*64 + c];
        permL[before + rank_in_wave] = tid;
        __syncthreads();

        // --- phase B: gather-reduce (wave owns 4 clusters)
        const int q   = lane & 7;
        const int sub = lane >> 3;
        const int fbase = fh*32 + q*4;
#pragma unroll
        for (int cc = 0; cc < 4; ++cc) {
            const int cl = w*4 + cc;
            const int s = startS[cl];
            const int e = startS[cl + 1];
            float ax = 0.f, ay = 0.f, az = 0.f, aw = 0.f, v2 = 0.f;
            for (int base = s + sub; base < e; base += 8) {
                const int n = g*kNPG + permL[base];
                const float v = varr[n];
                const float4 xv = *reinterpret_cast<const float4*>(
                    x + (size_t)n*kF + fbase);
                ax = fmaf(v, xv.x, ax); ay = fmaf(v, xv.y, ay);
                az = fmaf(v, xv.z, az); aw = fmaf(v, xv.w, aw);
                v2 = fmaf(v, v, v2);
            }
#pragma unroll
            for (int off = 8; off < 64; off <<= 1) {
                ax += __shfl_xor(ax, off); ay += __shfl_xor(ay, off);
                az += __shfl_xor(az, off); aw += __shfl_xor(aw, off);
                v2 += __shfl_xor(v2, off);
            }
            if (sub == 0) {
                const float4 o = {ax, ay, az, aw};
                *reinterpret_cast<float4*>(
                    out + OFF_OUT + (size_t)(g*kC + cl)*kF + fbase) = o;
            }
            if (fh == 0 && lane == 0) vs2[g*kC + cl] = v2;
        }
    } else {
        // ---------------- adj path: bid2 = bid-512; g = bid2>>3
        float* adj = (float*)smem;           // [4096]
        float* vls = adj + 4096;             // [1024]
        int*   cls = (int*)(vls + 1024);     // [1024]
        float* wred = (float*)(cls + 1024);  // [16]
        const int bid2 = bid - 512;
        const int g = bid2 >> 3;
        for (int i = tid; i < kC*kC; i += 1024) adj[i] = 0.f;
        vls[tid] = varr[g*kNPG + tid];
        cls[tid] = carr[g*kNPG + tid];
        __syncthreads();
        const int e0 = bid2 * 4096;
        float a2l = 0.f;
#pragma unroll
        for (int it = 0; it < 4; ++it) {
            const int e  = e0 + it*1024 + tid;
            const int sn = ei[e]      & (kNPG - 1);
            const int dn = ei[kE + e] & (kNPG - 1);
            const float wv = ew[e];
            a2l += wv * wv;
            atomicAdd(&adj[cls[sn]*kC + cls[dn]], wv * vls[sn] * vls[dn]);
        }
        __syncthreads();
#pragma unroll
        for (int r = 0; r < 4; ++r) {
            const int lin = r*1024 + tid;
            padj[(size_t)bid2*4096 + lin] = adj[lin];
        }
#pragma unroll
        for (int off = 32; off > 0; off >>= 1) a2l += __shfl_down(a2l, off);
        if ((tid & 63) == 0) wred[tid >> 6] = a2l;
        __syncthreads();
        if (tid == 0) {
            float s = 0.f;
#pragma unroll
            for (int wv = 0; wv < 16; ++wv) s += wred[wv];
            a2p[bid2] = s;
        }
    }
}

// ------------------------------------- K3: merge adj partials + diag sums
__global__ __launch_bounds__(256) void k_adj_merge(
    const float* __restrict__ padj, float* __restrict__ out,
    float* __restrict__ dsum)
{
    __shared__ float red[4];
    const int tid = threadIdx.x;
    const int id = blockIdx.x*256 + tid;   // < 262144
    const int g = id >> 12, idx = id & 4095;
    float s = 0.f;
#pragma unroll
    for (int sp = 0; sp < 8; ++sp) s += padj[(size_t)(g*8 + sp)*4096 + idx];
    out[OFF_ADJ + id] = s;
    float d = ((idx % 65) == 0) ? s : 0.f;
#pragma unroll
    for (int off = 32; off > 0; off >>= 1) d += __shfl_down(d, off);
    if ((tid & 63) == 0) red[tid >> 6] = d;
    __syncthreads();
    if (tid == 0) dsum[blockIdx.x] = red[0] + red[1] + red[2] + red[3];
}

// ------------------------------------- K4: link_loss scalar
__global__ __launch_bounds__(256) void k_final(
    const float* __restrict__ vs2, const float* __restrict__ a2p,
    const float* __restrict__ dsum, float* __restrict__ out)
{
    const int tid = threadIdx.x;
    float p2l = 0.f, apl = 0.f;
#pragma unroll
    for (int r = 0; r < 16; ++r) {
        const float t = vs2[r*256 + tid];
        p2l += t*t;
    }
#pragma unroll
    for (int r = 0; r < 4; ++r) apl += dsum[r*256 + tid];
    float a2l = a2p[tid] + a2p[tid + 256];
#pragma unroll
    for (int off = 32; off > 0; off >>= 1) {
        p2l += __shfl_down(p2l, off);
        apl += __shfl_down(apl, off);
        a2l += __shfl_down(a2l, off);
    }
    __shared__ float red[3][4];
    if ((tid & 63) == 0) {
        red[0][tid>>6] = p2l; red[1][tid>>6] = apl; red[2][tid>>6] = a2l;
    }
    __syncthreads();
    if (tid == 0) {
        const float p2 = red[0][0]+red[0][1]+red[0][2]+red[0][3];
        const float ap = red[1][0]+red[1][1]+red[1][2]+red[1][3];
        const float a2 = red[2][0]+red[2][1]+red[2][2]+red[2][3];
        const float val = a2 - 2.0f*ap + p2;
        out[OFF_LL] = sqrtf(fmaxf(val, 0.f)) / (float)kE;
        out[OFF_Z]  = 0.0f;
    }
}

// ----------------------------------------------------------------- launch
extern "C" void kernel_launch(void* const* d_in, const int* in_sizes, int n_in,
                              void* d_out, int out_size, void* d_ws, size_t ws_size,
                              hipStream_t stream)
{
    const float* x  = (const float*)d_in[0];
    const int*   ei = (const int*)d_in[1];
    const float* ew = (const float*)d_in[2];
    const float* Wm = (const float*)d_in[5];
    const float* bv = (const float*)d_in[6];
    float* out = (float*)d_out;
    char*  ws  = (char*)d_ws;
    int*   carr  = (int*)(ws + WS_C);
    float* varr  = (float*)(ws + WS_V);
    float* vs2   = (float*)(ws + WS_VS2);
    float* a2p   = (float*)(ws + WS_A2);
    unsigned short* wph = (unsigned short*)(ws + WS_WPH);
    unsigned short* wpl = (unsigned short*)(ws + WS_WPL);
    float* padj  = (float*)(ws + WS_PADJ);
    float* dsum  = (float*)(ws + WS_DSUM);

    k_const    <<<2193, 256, 0, stream>>>(out, Wm, wph, wpl);
    k_logits   <<<1024, 256, 0, stream>>>(x, wph, wpl, bv, carr, varr);
    k_fused    <<<1024, 1024, 0, stream>>>(x, carr, varr, ei, ew,
                                           out, vs2, padj, a2p);
    k_adj_merge<<<1024, 256, 0, stream>>>(padj, out, dsum);
    k_final    <<<1,    256, 0, stream>>>(vs2, a2p, dsum, out);
}

// Round 18
// 65.880 us; speedup vs baseline: 1.1611x; 1.0064x over previous
//
#include <hip/hip_runtime.h>
#include <cstdint>
#include <cstddef>

typedef __attribute__((ext_vector_type(8))) short short8;
typedef __attribute__((ext_vector_type(4))) float f32x4;

#define GLOAD_LDS16(gsrc, ldst) \
    __builtin_amdgcn_global_load_lds( \
        (const __attribute__((address_space(1))) void*)(gsrc), \
        (__attribute__((address_space(3))) void*)(ldst), 16, 0, 0)

namespace {
constexpr int kN    = 65536;     // nodes
constexpr int kF    = 256;       // feats
constexpr int kC    = 64;        // pools per graph
constexpr int kNPG  = 1024;      // nodes per graph
constexpr int kB    = 64;        // graphs
constexpr int kE    = 2097152;   // edges
constexpr int kK    = kB * kC;   // 4096 global clusters

// d_out offsets (in floats)
constexpr size_t OFF_OUT  = 0;                           // [4096,256]
constexpr size_t OFF_EIDX = (size_t)kK * kF;             // 1048576  [2,262144]
constexpr size_t OFF_ADJ  = OFF_EIDX + 2ull*kB*kC*kC;    // 1572864  [262144]
constexpr size_t OFF_LL   = OFF_ADJ + (size_t)kB*kC*kC;  // 1835008
constexpr size_t OFF_Z    = OFF_LL + 1;                  // 1835009
constexpr size_t OFF_BOUT = OFF_Z + 1;                   // 1835010  [4096]
constexpr size_t OFF_BPTR = OFF_BOUT + kK;               // 1839106  [65]

// ws offsets (bytes). WPH/WPL die after k_logits; k_fused then writes PADJ.
constexpr size_t WS_C    = 0;        // int[65536]
constexpr size_t WS_V    = 262144;   // float[65536]
constexpr size_t WS_VS2  = 524288;   // float[4096]
constexpr size_t WS_A2   = 540672;   // float[256]
constexpr size_t WS_WPH  = 1048576;  // ushort[16384] W frag-packed hi
constexpr size_t WS_WPL  = 1081344;  // ushort[16384] W frag-packed lo
constexpr size_t WS_PADJ = 1114112;  // float[256*4096] = 4 MiB
constexpr size_t WS_DSUM = 9502720;  // float[1024] diag partials

__device__ __forceinline__ unsigned short bf16_rn(float f)
{
    const unsigned int b = __float_as_uint(f);
    return (unsigned short)((b + 0x7fffu + ((b >> 16) & 1u)) >> 16);
}
} // namespace

// ---------------------------------------------------------------- constants
// + packs W into MFMA B-fragment order, bf16 hi/lo.
__global__ __launch_bounds__(256) void k_const(float* __restrict__ out,
                                               const float* __restrict__ Wm,
                                               unsigned short* __restrict__ wph,
                                               unsigned short* __restrict__ wpl)
{
    const int i = blockIdx.x * 256 + threadIdx.x;
    constexpr int E2 = 2 * kB * kC * kC;      // 524288
    constexpr int B3 = E2 + kK + kB + 1;      // 528449
    if (i < E2) {
        const int half = i >= kB*kC*kC;
        const int idx  = half ? i - kB*kC*kC : i;
        const int bb = idx >> 12, rem = idx & 4095;
        const int val = half ? bb*kC + (rem & 63) : bb*kC + (rem >> 6);
        out[OFF_EIDX + i] = (float)val;
    } else if (i < E2 + kK) {
        const int j = i - E2;
        out[OFF_BOUT + j] = (float)(j >> 6);
    } else if (i < B3) {
        const int j = i - (E2 + kK);
        out[OFF_BPTR + j] = (float)(j * kC);
    } else if (i < B3 + 32768) {
        const int j  = (i - B3) & 16383;
        const int lo = (i - B3) >= 16384;
        const int jj = j & 7, lane = (j >> 3) & 63;
        const int nt = (j >> 9) & 3, ks = j >> 11;
        const float wv = Wm[(size_t)(ks*32 + (lane>>4)*8 + jj)*kC
                            + nt*16 + (lane & 15)];
        const unsigned short h = bf16_rn(wv);
        if (!lo) {
            wph[j] = h;
        } else {
            const float hf = __uint_as_float((unsigned int)h << 16);
            wpl[j] = bf16_rn(wv - hf);
        }
    }
}

// ------------------------------------------------- K1: logits -> c, v
// (round-16 structure, unchanged: W in LDS via one-time prologue; barrier-
// free main loop; per-wave x double-buffer with counted vmcnt(2); T2.)
__global__ __launch_bounds__(256) void k_logits(
    const float* __restrict__ x, const unsigned short* __restrict__ wph,
    const unsigned short* __restrict__ wpl, const float* __restrict__ bv,
    int* __restrict__ carr, float* __restrict__ varr)
{
    __shared__ unsigned short wlds[32768];   // 64 KB: [0..16383]=hi, rest=lo
    __shared__ float xsl[2][64 * 32];        // 2 x 8 KB
    const int tid  = threadIdx.x;
    const int lane = tid & 63;
    const int w    = tid >> 6;
    const int nbase = blockIdx.x * 64;
    const int l15  = lane & 15;
    const int kgrp = lane >> 4;

    const int snode = lane >> 3;
    const int sfo   = ((lane & 7) ^ snode) * 4;

    f32x4 acc[4];
#pragma unroll
    for (int nt = 0; nt < 4; ++nt) acc[nt] = f32x4{0.f, 0.f, 0.f, 0.f};

#pragma unroll
    for (int t = 0; t < 8; ++t) {
        GLOAD_LDS16(wph + ((size_t)t*256 + tid)*8, &wlds[(t*256 + w*64)*8]);
        GLOAD_LDS16(wpl + ((size_t)t*256 + tid)*8,
                    &wlds[16384 + (t*256 + w*64)*8]);
    }
#pragma unroll
    for (int i = 0; i < 2; ++i) {
        const float* src = x + (size_t)(nbase + w*16 + i*8 + snode)*kF + sfo;
        GLOAD_LDS16(src, &xsl[0][(w*16 + i*8)*32]);
    }
    asm volatile("s_waitcnt vmcnt(0)" ::: "memory");
    __syncthreads();

#pragma unroll 1
    for (int c = 0; c < 8; ++c) {
        if (c < 7) {
#pragma unroll
            for (int i = 0; i < 2; ++i) {
                const float* src = x + (size_t)(nbase + w*16 + i*8 + snode)*kF
                                     + (c+1)*32 + sfo;
                GLOAD_LDS16(src, &xsl[(c+1) & 1][(w*16 + i*8)*32]);
            }
            asm volatile("s_waitcnt vmcnt(2)" ::: "memory");
        } else {
            asm volatile("s_waitcnt vmcnt(0)" ::: "memory");
        }

        const float* __restrict__ xb = &xsl[c & 1][0];
        short8 bh[4], bl[4];
#pragma unroll
        for (int nt = 0; nt < 4; ++nt) {
            const int wo = ((c*4 + nt)*64 + lane) * 8;
            bh[nt] = *reinterpret_cast<const short8*>(&wlds[wo]);
            bl[nt] = *reinterpret_cast<const short8*>(&wlds[16384 + wo]);
        }
        const int row = w*16 + l15;
        const int sA  = ((kgrp*2)     ^ (l15 & 7)) * 4;
        const int sC  = ((kgrp*2 + 1) ^ (l15 & 7)) * 4;
        const float4 xa = *reinterpret_cast<const float4*>(&xb[row*32 + sA]);
        const float4 xc = *reinterpret_cast<const float4*>(&xb[row*32 + sC]);
        const float xv[8] = {xa.x, xa.y, xa.z, xa.w,
                             xc.x, xc.y, xc.z, xc.w};
        short8 ah, al;
#pragma unroll
        for (int j = 0; j < 8; ++j) {
            const unsigned short h = bf16_rn(xv[j]);
            const float hf = __uint_as_float((unsigned int)h << 16);
            ah[j] = (short)h;
            al[j] = (short)bf16_rn(xv[j] - hf);
        }
#pragma unroll
        for (int nt = 0; nt < 4; ++nt) {
            acc[nt] = __builtin_amdgcn_mfma_f32_16x16x32_bf16(
                ah, bh[nt], acc[nt], 0, 0, 0);
            acc[nt] = __builtin_amdgcn_mfma_f32_16x16x32_bf16(
                al, bh[nt], acc[nt], 0, 0, 0);
            acc[nt] = __builtin_amdgcn_mfma_f32_16x16x32_bf16(
                ah, bl[nt], acc[nt], 0, 0, 0);
            acc[nt] = __builtin_amdgcn_mfma_f32_16x16x32_bf16(
                al, bl[nt], acc[nt], 0, 0, 0);
        }
    }

#pragma unroll
    for (int nt = 0; nt < 4; ++nt) {
        const float b = bv[nt*16 + l15];
#pragma unroll
        for (int r = 0; r < 4; ++r) acc[nt][r] += b;
    }
#pragma unroll
    for (int r = 0; r < 4; ++r) {
        float m = acc[0][r]; int ci = l15;
#pragma unroll
        for (int nt = 1; nt < 4; ++nt) {
            if (acc[nt][r] > m) { m = acc[nt][r]; ci = nt*16 + l15; }
        }
#pragma unroll
        for (int off = 1; off < 16; off <<= 1) {
            const float om = __shfl_xor(m, off);
            const int   oc = __shfl_xor(ci, off);
            if (om > m || (om == m && oc < ci)) { m = om; ci = oc; }
        }
        float s = 0.f;
#pragma unroll
        for (int nt = 0; nt < 4; ++nt) s += expf(acc[nt][r] - m);
#pragma unroll
        for (int off = 1; off < 16; off <<= 1) s += __shfl_xor(s, off);
        if (l15 == r) {
            const float p = 1.0f / s;
            const int n = nbase + w*16 + kgrp*4 + r;
            carr[n] = ci;
            varr[n] = (1.0f - p) + p;
        }
    }
}

// ------------------------------------- K2: fused adj+pool (768 blocks)
// bid < 256:  adjacency partials (+ a2) — 8192 edges each. Dispatched
//             FIRST so the LDS-atomic-bound long pole overlaps the
//             HBM-bound pool blocks instead of trailing them.
// bid >= 256: out = S^T x (+ vs2) with in-block counting sort.
__global__ __launch_bounds__(1024) void k_fused(
    const float* __restrict__ x, const int* __restrict__ carr,
    const float* __restrict__ varr, const int* __restrict__ ei,
    const float* __restrict__ ew, float* __restrict__ out,
    float* __restrict__ vs2, float* __restrict__ padj,
    float* __restrict__ a2p)
{
    __shared__ char smem[25152];
    const int tid = threadIdx.x;
    const int bid = blockIdx.x;

    if (bid < 256) {
        // ---------------- adj path: g = bid>>2, 8192 edges
        float* adj = (float*)smem;           // [4096]
        float* vls = adj + 4096;             // [1024]
        int*   cls = (int*)(vls + 1024);     // [1024]
        float* wred = (float*)(cls + 1024);  // [16]
        const int g = bid >> 2;
        for (int i = tid; i < kC*kC; i += 1024) adj[i] = 0.f;
        vls[tid] = varr[g*kNPG + tid];
        cls[tid] = carr[g*kNPG + tid];
        __syncthreads();
        const int e0 = bid * 8192;
        float a2l = 0.f;
#pragma unroll
        for (int it = 0; it < 8; ++it) {
            const int e  = e0 + it*1024 + tid;
            const int sn = ei[e]      & (kNPG - 1);
            const int dn = ei[kE + e] & (kNPG - 1);
            const float wv = ew[e];
            a2l += wv * wv;
            atomicAdd(&adj[cls[sn]*kC + cls[dn]], wv * vls[sn] * vls[dn]);
        }
        __syncthreads();
#pragma unroll
        for (int r = 0; r < 4; ++r) {
            const int lin = r*1024 + tid;
            padj[(size_t)bid*4096 + lin] = adj[lin];
        }
#pragma unroll
        for (int off = 32; off > 0; off >>= 1) a2l += __shfl_down(a2l, off);
        if ((tid & 63) == 0) wred[tid >> 6] = a2l;
        __syncthreads();
        if (tid == 0) {
            float s = 0.f;
#pragma unroll
            for (int wv = 0; wv < 16; ++wv) s += wred[wv];
            a2p[bid] = s;
        }
    } else {
        // ---------------- pool path: pbid = bid-256
        int* hist   = (int*)smem;            // [16][64]
        int* startS = hist + 1024;           // [65]
        int* permL  = startS + 80;           // [1024]
        const int pbid = bid - 256;
        const int g  = pbid >> 3;
        const int fh = pbid & 7;
        const int w = tid >> 6, lane = tid & 63;

        // --- phase A: counting sort (ballot algorithm, deterministic)
        const int c = carr[g*kNPG + tid];
        hist[tid] = 0;
        __syncthreads();
        unsigned long long mm = ~0ull;
#pragma unroll
        for (int b = 0; b < 6; ++b) {
            const unsigned long long bal = __ballot((c >> b) & 1);
            mm &= ((c >> b) & 1) ? bal : ~bal;
        }
        const unsigned long long ltmask =
            (lane == 0) ? 0ull : (~0ull >> (64 - lane));
        const int rank_in_wave = __popcll(mm & ltmask);
        const int leader = __ffsll((unsigned long long)mm) - 1;
        if (lane == leader) hist[w*64 + c] = __popcll(mm);
        __syncthreads();
        if (w == 0) {
            int tot = 0;
#pragma unroll
            for (int i = 0; i < 16; ++i) tot += hist[i*64 + lane];
            int pre = tot;
#pragma unroll
            for (int off = 1; off < 64; off <<= 1) {
                const int t = __shfl_up(pre, off);
                if (lane >= off) pre += t;
            }
            startS[lane + 1] = pre;
            if (lane == 0) startS[0] = 0;
        }
        __syncthreads();
        int before = startS[c];
        for (int i = 0; i < w; ++i) before += hist[i*64 + c];
        permL[before + rank_in_wave] = tid;
        __syncthreads();

        // --- phase B: gather-reduce (wave owns 4 clusters)
        const int q   = lane & 7;
        const int sub = lane >> 3;
        const int fbase = fh*32 + q*4;
#pragma unroll
        for (int cc = 0; cc < 4; ++cc) {
            const int cl = w*4 + cc;
            const int s = startS[cl];
            const int e = startS[cl + 1];
            float ax = 0.f, ay = 0.f, az = 0.f, aw = 0.f, v2 = 0.f;
            for (int base = s + sub; base < e; base += 8) {
                const int n = g*kNPG + permL[base];
                const float v = varr[n];
                const float4 xv = *reinterpret_cast<const float4*>(
                    x + (size_t)n*kF + fbase);
                ax = fmaf(v, xv.x, ax); ay = fmaf(v, xv.y, ay);
                az = fmaf(v, xv.z, az); aw = fmaf(v, xv.w, aw);
                v2 = fmaf(v, v, v2);
            }
#pragma unroll
            for (int off = 8; off < 64; off <<= 1) {
                ax += __shfl_xor(ax, off); ay += __shfl_xor(ay, off);
                az += __shfl_xor(az, off); aw += __shfl_xor(aw, off);
                v2 += __shfl_xor(v2, off);
            }
            if (sub == 0) {
                const float4 o = {ax, ay, az, aw};
                *reinterpret_cast<float4*>(
                    out + OFF_OUT + (size_t)(g*kC + cl)*kF + fbase) = o;
            }
            if (fh == 0 && lane == 0) vs2[g*kC + cl] = v2;
        }
    }
}

// ------------------------------------- K3: merge adj partials + diag sums
__global__ __launch_bounds__(256) void k_adj_merge(
    const float* __restrict__ padj, float* __restrict__ out,
    float* __restrict__ dsum)
{
    __shared__ float red[4];
    const int tid = threadIdx.x;
    const int id = blockIdx.x*256 + tid;   // < 262144
    const int g = id >> 12, idx = id & 4095;
    float s = 0.f;
#pragma unroll
    for (int sp = 0; sp < 4; ++sp) s += padj[(size_t)(g*4 + sp)*4096 + idx];
    out[OFF_ADJ + id] = s;
    float d = ((idx % 65) == 0) ? s : 0.f;
#pragma unroll
    for (int off = 32; off > 0; off >>= 1) d += __shfl_down(d, off);
    if ((tid & 63) == 0) red[tid >> 6] = d;
    __syncthreads();
    if (tid == 0) dsum[blockIdx.x] = red[0] + red[1] + red[2] + red[3];
}

// ------------------------------------- K4: link_loss scalar
__global__ __launch_bounds__(256) void k_final(
    const float* __restrict__ vs2, const float* __restrict__ a2p,
    const float* __restrict__ dsum, float* __restrict__ out)
{
    const int tid = threadIdx.x;
    float p2l = 0.f, apl = 0.f;
#pragma unroll
    for (int r = 0; r < 16; ++r) {
        const float t = vs2[r*256 + tid];
        p2l += t*t;
    }
#pragma unroll
    for (int r = 0; r < 4; ++r) apl += dsum[r*256 + tid];
    float a2l = a2p[tid];
#pragma unroll
    for (int off = 32; off > 0; off >>= 1) {
        p2l += __shfl_down(p2l, off);
        apl += __shfl_down(apl, off);
        a2l += __shfl_down(a2l, off);
    }
    __shared__ float red[3][4];
    if ((tid & 63) == 0) {
        red[0][tid>>6] = p2l; red[1][tid>>6] = apl; red[2][tid>>6] = a2l;
    }
    __syncthreads();
    if (tid == 0) {
        const float p2 = red[0][0]+red[0][1]+red[0][2]+red[0][3];
        const float ap = red[1][0]+red[1][1]+red[1][2]+red[1][3];
        const float a2 = red[2][0]+red[2][1]+red[2][2]+red[2][3];
        const float val = a2 - 2.0f*ap + p2;
        out[OFF_LL] = sqrtf(fmaxf(val, 0.f)) / (float)kE;
        out[OFF_Z]  = 0.0f;
    }
}

// ----------------------------------------------------------------- launch
extern "C" void kernel_launch(void* const* d_in, const int* in_sizes, int n_in,
                              void* d_out, int out_size, void* d_ws, size_t ws_size,
                              hipStream_t stream)
{
    const float* x  = (const float*)d_in[0];
    const int*   ei = (const int*)d_in[1];
    const float* ew = (const float*)d_in[2];
    const float* Wm = (const float*)d_in[5];
    const float* bv = (const float*)d_in[6];
    float* out = (float*)d_out;
    char*  ws  = (char*)d_ws;
    int*   carr  = (int*)(ws + WS_C);
    float* varr  = (float*)(ws + WS_V);
    float* vs2   = (float*)(ws + WS_VS2);
    float* a2p   = (float*)(ws + WS_A2);
    unsigned short* wph = (unsigned short*)(ws + WS_WPH);
    unsigned short* wpl = (unsigned short*)(ws + WS_WPL);
    float* padj  = (float*)(ws + WS_PADJ);
    float* dsum  = (float*)(ws + WS_DSUM);

    k_const    <<<2193, 256, 0, stream>>>(out, Wm, wph, wpl);
    k_logits   <<<1024, 256, 0, stream>>>(x, wph, wpl, bv, carr, varr);
    k_fused    <<<768, 1024, 0, stream>>>(x, carr, varr, ei, ew,
                                          out, vs2, padj, a2p);
    k_adj_merge<<<1024, 256, 0, stream>>>(padj, out, dsum);
    k_final    <<<1,    256, 0, stream>>>(vs2, a2p, dsum, out);
}